// Round 21
// baseline (28.687 us; speedup 1.0000x reference)
//
#include <hip/hip_runtime.h>
#include <hip/hip_fp16.h>
#include <math.h>

#define NMODES 4096
#define NGRID  8192
#define BATCH  16
#define NPTS   131072
#define GSTRIDE 8200                    // 8192 + 8 wrap cells (u32 each); %4==0
#define GSCALE 1048576.0f               // 2^20 (exact)
#define OSCALE 1.5178830414797062e-07f  // 1/(2*pi*2^20)

struct AMat { float a[48]; };           // a[(l-1)*8 + d], taps l=1..6, deg d=0..7

__device__ __forceinline__ float2 cmul(float2 a, float2 b) {
    return make_float2(a.x * b.x - a.y * b.y, a.x * b.y + a.y * b.x);
}

// ---------------------------------------------------------------------------
// Deconvolution factor: (-1)^fidx / phi_hat(fidx), I0 asymptotic (z~18).
// ---------------------------------------------------------------------------
__device__ __forceinline__ float deconv_signed(int fidx) {
    float k = (float)(fidx - 2048);
    float t = k * 7.66990393942820614e-4f;                 // 2*pi*k/n
    float z = 4.0f * sqrtf(22.2066099024510563f - t * t);  // m*sqrt(b^2-t^2)
    float iz = 1.0f / z;
    float p  = 1.0f + iz * (0.125f + iz * (0.0703125f +
               iz * (0.0732421875f + iz * 0.112152099609375f)));
    float phi = __expf(z) * p * rsqrtf(6.28318530717958648f * z);
    float s = (fidx & 1) ? -1.0f : 1.0f;
    return s / phi;
}

// ---------------------------------------------------------------------------
// Merged four-step FFT, 512 threads (byte-identical to green R20).
// ---------------------------------------------------------------------------
__global__ __launch_bounds__(512) void nfft_fft_kernel(
    const float* __restrict__ fr, const float* __restrict__ fi,
    __half2* __restrict__ g16)
{
    __shared__ float2 hbuf[NMODES];  // 32 KB
    __shared__ float2 fbuf[512];     // 4 KB
    __shared__ float2 w16[16];

    const int b   = blockIdx.x >> 4;
    const int k1  = blockIdx.x & 15;
    const int tid = threadIdx.x;     // 0..511

    if (tid < 16) {
        float tn = -(float)tid * 0.0625f;   // -t/16 turns
        w16[tid] = make_float2(__builtin_amdgcn_cosf(tn),
                               __builtin_amdgcn_sinf(tn));
    }
#pragma unroll
    for (int i = 0; i < 8; ++i) {
        int fidx = tid + i * 512;
        float inv = deconv_signed(fidx);
        hbuf[fidx] = make_float2(fr[b * NMODES + fidx] * inv,
                                 fi[b * NMODES + fidx] * inv);
    }
    __syncthreads();

    {
        int n2 = tid;
        float2 acc = make_float2(0.0f, 0.0f);
#pragma unroll
        for (int r = 0; r < 8; ++r) {
            float2 w = w16[((r + 4) * k1) & 15];
            float2 h = hbuf[n2 + 512 * r];
            acc.x = fmaf(h.x, w.x, fmaf(-h.y, w.y, acc.x));
            acc.y = fmaf(h.x, w.y, fmaf( h.y, w.x, acc.y));
        }
        float tn = -(float)(n2 * k1) * 1.220703125e-4f;
        float2 tw = make_float2(__builtin_amdgcn_cosf(tn),
                                __builtin_amdgcn_sinf(tn));
        int rb = (int)(__brev((unsigned)n2) >> 23);
        fbuf[rb] = cmul(acc, tw);
    }
    __syncthreads();

    for (int s = 0; s <= 8; ++s) {
        const int   half = 1 << s;
        const float tscl = -0.5f / (float)half;
        if (tid < 256) {
            int pos = tid & (half - 1);
            int idx = ((tid ^ pos) << 1) | pos;
            float sn = __builtin_amdgcn_sinf(tscl * (float)pos);
            float cs = __builtin_amdgcn_cosf(tscl * (float)pos);
            float2 a = fbuf[idx];
            float2 t = fbuf[idx + half];
            float2 bt = make_float2(t.x * cs - t.y * sn,
                                    t.x * sn + t.y * cs);
            fbuf[idx]        = make_float2(a.x + bt.x, a.y + bt.y);
            fbuf[idx + half] = make_float2(a.x - bt.x, a.y - bt.y);
        }
        __syncthreads();
    }

    const float s2 = ((k1 & 1) ? -1.0f : 1.0f) * GSCALE;
    __half2* base = g16 + b * GSTRIDE + k1;
    {
        int j = tid;
        float2 v = fbuf[j];
        base[16 * j] = __floats2half2_rn(v.x * s2, v.y * s2);
    }
    if (tid == 0 && k1 < 8) {
        float2 v = fbuf[0];
        g16[b * GSTRIDE + NGRID + k1] = __floats2half2_rn(v.x * s2, v.y * s2);
    }
}

// ---------------------------------------------------------------------------
// Conv kernel: P_d[c] = sum_l A[l][d] * Re(g16[c+l]), d=0..7. One thread per
// (batch,cell); coalesced streaming loads/stores; named scalars only.
// ---------------------------------------------------------------------------
__global__ __launch_bounds__(1024) void nfft_conv_kernel(
    const __half2* __restrict__ g16, float4* __restrict__ P, AMat A)
{
    const int gid = blockIdx.x * 1024 + threadIdx.x;  // 0..131071
    const int b   = gid >> 13;
    const int c   = gid & (NGRID - 1);
    const __half2* gb = g16 + b * GSTRIDE + c;

    float g1 = __low2float(gb[1]);
    float g2 = __low2float(gb[2]);
    float g3 = __low2float(gb[3]);
    float g4 = __low2float(gb[4]);
    float g5 = __low2float(gb[5]);
    float g6 = __low2float(gb[6]);

#define PD(d) (A.a[0*8+(d)]*g1 + A.a[1*8+(d)]*g2 + A.a[2*8+(d)]*g3 + \
               A.a[3*8+(d)]*g4 + A.a[4*8+(d)]*g5 + A.a[5*8+(d)]*g6)
    float p0 = PD(0), p1 = PD(1), p2 = PD(2), p3 = PD(3);
    float p4 = PD(4), p5 = PD(5), p6 = PD(6), p7 = PD(7);
#undef PD
    P[gid * 2]     = make_float4(p0, p1, p2, p3);
    P[gid * 2 + 1] = make_float4(p4, p5, p6, p7);
}

// ---------------------------------------------------------------------------
// Poly interp (cplx=0): per point ONE aligned 32B read (2 dwordx4, same 64B
// line) + 7-fma Horner. No exp/rsqrt, no scattered dwords.
// ---------------------------------------------------------------------------
__global__ __launch_bounds__(1024) void nfft_interp_poly_kernel(
    const float* __restrict__ x, const float4* __restrict__ P,
    float* __restrict__ out)
{
    const int b   = blockIdx.x & 15;
    const int blk = blockIdx.x >> 4;
    const int tid = threadIdx.x;

    const float4* Pb = P + (size_t)b * NGRID * 2;
    const int base = b * NPTS + blk * 4096;
    const float4 xv4 = ((const float4*)(x + base))[tid];
    float o0, o1, o2, o3;

#define POLY_PT(XV, OUTV) do {                                      \
        float fl   = (XV) * 8192.0f;                                \
        float cf   = ceilf(fl);                                     \
        int   c    = (int)cf;                                       \
        float f_   = cf - fl;                                       \
        int   wr0  = (c + 12284) & (NGRID - 1);                     \
        float4 pa = Pb[wr0 * 2];                                    \
        float4 pb = Pb[wr0 * 2 + 1];                                \
        float h = pb.w;                                             \
        h = fmaf(h, f_, pb.z); h = fmaf(h, f_, pb.y);               \
        h = fmaf(h, f_, pb.x); h = fmaf(h, f_, pa.w);               \
        h = fmaf(h, f_, pa.z); h = fmaf(h, f_, pa.y);               \
        h = fmaf(h, f_, pa.x);                                      \
        (OUTV) = h;                                                 \
    } while (0)
    POLY_PT(xv4.x, o0); POLY_PT(xv4.y, o1);
    POLY_PT(xv4.z, o2); POLY_PT(xv4.w, o3);
#undef POLY_PT
    ((float4*)(out + base))[tid] = make_float4(o0, o1, o2, o3);
}

// ---------------------------------------------------------------------------
// Interp fallback — byte-identical to green R20 (handles cplx too).
// ---------------------------------------------------------------------------
__global__ __launch_bounds__(1024) void nfft_interp_kernel(
    const float* __restrict__ x, const __half2* __restrict__ g16,
    float* __restrict__ out, int cplx)
{
    const int b   = blockIdx.x & 15;
    const int blk = blockIdx.x >> 4;
    const int tid = threadIdx.x;

    const __half2* gb = g16 + b * GSTRIDE;
    const int base = b * NPTS + blk * 4096;
    const float4 xv4 = ((const float4*)(x + base))[tid];
    float outre[4], outim[4];

#pragma unroll
    for (int q = 0; q < 4; ++q) {
        float xv = (q == 0) ? xv4.x : (q == 1) ? xv4.y : (q == 2) ? xv4.z : xv4.w;
        float fl   = xv * 8192.0f;
        float cf   = ceilf(fl);
        int   c    = (int)cf;
        float frac = cf - fl;
        int   wr0  = (c + 12284) & (NGRID - 1);
        const __half2* gp = gb + wr0;
        float re = 0.0f, im = 0.0f;
#pragma unroll
        for (int l = 1; l < 7; ++l) {
            float u    = (float)(4 - l) - frac;
            float arg2 = fmaf(-u, u, 16.0f);
            float r    = rsqrtf(arg2);
            float z    = arg2 * r * 4.71238898038468986f;
            float w    = __expf(z) * r;
            float2 gv = __half22float2(gp[l]);
            re = fmaf(w, gv.x, re);
            im = fmaf(w, gv.y, im);
        }
        outre[q] = re * OSCALE;
        outim[q] = im * OSCALE;
    }

    if (cplx) {
        float2* o = ((float2*)out) + base + tid * 4;
        o[0] = make_float2(outre[0], outim[0]);
        o[1] = make_float2(outre[1], outim[1]);
        o[2] = make_float2(outre[2], outim[2]);
        o[3] = make_float2(outre[3], outim[3]);
    } else {
        ((float4*)(out + base))[tid] =
            make_float4(outre[0], outre[1], outre[2], outre[3]);
    }
}

// ---------------------------------------------------------------------------
// Fused single-kernel fallback (proven R4/R7) if d_ws too small.
// ---------------------------------------------------------------------------
__global__ __launch_bounds__(1024) void nfft_fused_kernel(
    const float* __restrict__ x, const float* __restrict__ fr,
    const float* __restrict__ fi, float* __restrict__ out, int cplx)
{
    __shared__ float2 buf[NGRID];
    const int b   = blockIdx.x >> 5;
    const int blk = blockIdx.x & 31;
    const int tid = threadIdx.x;

    for (int j = tid; j < NGRID; j += 1024) {
        float2 v = make_float2(0.0f, 0.0f);
        if (j >= 2048 && j < 6144) {
            int fidx = j - 2048;
            float inv = deconv_signed(fidx);
            v.x = fr[b * NMODES + fidx] * inv;
            v.y = fi[b * NMODES + fidx] * inv;
        }
        buf[j] = v;
    }
    __syncthreads();

    for (int s = 12; s >= 0; --s) {
        const int   half = 1 << s;
        const float tscl = -0.5f / (float)half;
#pragma unroll
        for (int ii = 0; ii < 4; ++ii) {
            int i = tid + ii * 1024;
            int pos = i & (half - 1);
            int idx = ((i ^ pos) << 1) | pos;
            float sn = __builtin_amdgcn_sinf(tscl * (float)pos);
            float cs = __builtin_amdgcn_cosf(tscl * (float)pos);
            float2 a = buf[idx];
            float2 c = buf[idx + half];
            buf[idx] = make_float2(a.x + c.x, a.y + c.y);
            float2 d = make_float2(a.x - c.x, a.y - c.y);
            buf[idx + half] = make_float2(d.x * cs - d.y * sn,
                                          d.x * sn + d.y * cs);
        }
        __syncthreads();
    }

    const int base = b * NPTS + blk * 4096;
    for (int p = tid; p < 4096; p += 1024) {
        float xv   = x[base + p];
        float fl   = xv * 8192.0f;
        int   c    = (int)ceilf(fl);
        float frac = (float)c - fl;
        float re = 0.0f, im = 0.0f;
#pragma unroll
        for (int l = 0; l < 8; ++l) {
            int   ind  = c - 4 + l;
            float u    = (float)(4 - l) - frac;
            float arg2 = 16.0f - u * u;
            float w    = 0.0f;
            if (arg2 > 0.0f) {
                float r   = rsqrtf(arg2);
                float arg = arg2 * r;
                float z   = 4.71238898038468986f * arg;
                w = (__expf(z) - __expf(-z)) * 0.15915494309189533577f * r;
            }
            if (ind & 1) w = -w;
            int wr = (ind + 4096) & (NGRID - 1);
            int rb = (int)(__brev((unsigned)wr) >> 19);
            float2 gv = buf[rb];
            re = fmaf(w, gv.x, re);
            im = fmaf(w, gv.y, im);
        }
        if (cplx) ((float2*)out)[base + p] = make_float2(re, im);
        else      out[base + p] = re;
    }
}

// ---------------------------------------------------------------------------
// Host: degree-7 interpolation of the 6 tap windows at Chebyshev nodes.
// Pure function of constants -> deterministic each call.
// ---------------------------------------------------------------------------
static void nfft_compute_amat(AMat* M) {
    const double PI = 3.14159265358979323846;
    const double bb = 1.5 * PI;
    const double osc = 1.0 / (2.0 * PI * 1048576.0);
    double t[8];
    for (int i = 0; i < 8; ++i)
        t[i] = 0.5 - 0.5 * cos(PI * (2.0 * i + 1.0) / 16.0);
    for (int l = 1; l <= 6; ++l) {
        double W[8][9];
        for (int i = 0; i < 8; ++i) {
            double pw = 1.0;
            for (int d = 0; d < 8; ++d) { W[i][d] = pw; pw *= t[i]; }
            double u   = (double)(4 - l) - t[i];
            double arg = sqrt(16.0 - u * u);          // >= sqrt(7) > 0
            W[i][8] = osc * exp(bb * arg) / arg;      // matches device window
        }
        for (int col = 0; col < 8; ++col) {           // Gauss, partial pivot
            int piv = col;
            for (int r2 = col + 1; r2 < 8; ++r2)
                if (fabs(W[r2][col]) > fabs(W[piv][col])) piv = r2;
            if (piv != col)
                for (int cc = col; cc < 9; ++cc) {
                    double tmp = W[col][cc]; W[col][cc] = W[piv][cc]; W[piv][cc] = tmp;
                }
            for (int r2 = col + 1; r2 < 8; ++r2) {
                double f = W[r2][col] / W[col][col];
                for (int cc = col; cc < 9; ++cc) W[r2][cc] -= f * W[col][cc];
            }
        }
        double a[8];
        for (int row = 7; row >= 0; --row) {
            double s = W[row][8];
            for (int cc = row + 1; cc < 8; ++cc) s -= W[row][cc] * a[cc];
            a[row] = s / W[row][row];
        }
        for (int d = 0; d < 8; ++d) M->a[(l - 1) * 8 + d] = (float)a[d];
    }
}

extern "C" void kernel_launch(void* const* d_in, const int* in_sizes, int n_in,
                              void* d_out, int out_size, void* d_ws, size_t ws_size,
                              hipStream_t stream) {
    (void)in_sizes; (void)n_in;
    const float* x  = (const float*)d_in[0];
    const float* fr = (const float*)d_in[1];
    const float* fi = (const float*)d_in[2];

    const int cplx = (out_size >= BATCH * NPTS * 2) ? 1 : 0;
    const size_t g_bytes = (size_t)BATCH * GSTRIDE * sizeof(__half2);   // 524,800
    const size_t p_off   = g_bytes;                                     // 256-aligned
    const size_t p_bytes = (size_t)BATCH * NGRID * 8 * sizeof(float);   // 4 MB

    if (!cplx && ws_size >= p_off + p_bytes) {
        __half2* g16 = (__half2*)d_ws;
        float4*  P   = (float4*)((char*)d_ws + p_off);
        AMat A;
        nfft_compute_amat(&A);
        nfft_fft_kernel<<<BATCH * 16, 512, 0, stream>>>(fr, fi, g16);
        nfft_conv_kernel<<<128, 1024, 0, stream>>>(g16, P, A);
        nfft_interp_poly_kernel<<<BATCH * 32, 1024, 0, stream>>>(
            x, P, (float*)d_out);
    } else if (ws_size >= g_bytes) {
        __half2* g16 = (__half2*)d_ws;
        nfft_fft_kernel<<<BATCH * 16, 512, 0, stream>>>(fr, fi, g16);
        nfft_interp_kernel<<<BATCH * 32, 1024, 0, stream>>>(
            x, g16, (float*)d_out, cplx);
    } else {
        nfft_fused_kernel<<<BATCH * 32, 1024, 0, stream>>>(
            x, fr, fi, (float*)d_out, cplx);
    }
}

// Round 22
// 20.827 us; speedup vs baseline: 1.3774x; 1.3774x over previous
//
#include <hip/hip_runtime.h>
#include <hip/hip_fp16.h>
#include <math.h>

#define NMODES 4096
#define NGRID  8192
#define BATCH  16
#define NPTS   131072
#define GSTRIDE 8200                    // 8192 + 8 wrap cells; %4==0
#define GSCALE 1048576.0f               // 2^20 (exact)
#define OSCALE 1.5178830414797062e-07f  // 1/(2*pi*2^20)

__device__ __forceinline__ float2 cmul(float2 a, float2 b) {
    return make_float2(a.x * b.x - a.y * b.y, a.x * b.y + a.y * b.x);
}

// ---------------------------------------------------------------------------
// Deconvolution factor: (-1)^fidx / phi_hat(fidx), I0 asymptotic (z~18).
// ---------------------------------------------------------------------------
__device__ __forceinline__ float deconv_signed(int fidx) {
    float k = (float)(fidx - 2048);
    float t = k * 7.66990393942820614e-4f;                 // 2*pi*k/n
    float z = 4.0f * sqrtf(22.2066099024510563f - t * t);  // m*sqrt(b^2-t^2)
    float iz = 1.0f / z;
    float p  = 1.0f + iz * (0.125f + iz * (0.0703125f +
               iz * (0.0732421875f + iz * 0.112152099609375f)));
    float phi = __expf(z) * p * rsqrtf(6.28318530717958648f * z);
    float s = (fidx & 1) ? -1.0f : 1.0f;
    return s / phi;
}

// ---------------------------------------------------------------------------
// Merged four-step FFT, 512 threads (R20 green) + one extra output: a
// re-only fp16 slab gr16 (2 B/cell, 16.4 KB/batch) for the cplx=0 interp.
// ---------------------------------------------------------------------------
__global__ __launch_bounds__(512) void nfft_fft_kernel(
    const float* __restrict__ fr, const float* __restrict__ fi,
    __half2* __restrict__ g16, __half* __restrict__ gr16)
{
    __shared__ float2 hbuf[NMODES];  // 32 KB
    __shared__ float2 fbuf[512];     // 4 KB
    __shared__ float2 w16[16];

    const int b   = blockIdx.x >> 4;
    const int k1  = blockIdx.x & 15;
    const int tid = threadIdx.x;     // 0..511

    if (tid < 16) {
        float tn = -(float)tid * 0.0625f;   // -t/16 turns
        w16[tid] = make_float2(__builtin_amdgcn_cosf(tn),
                               __builtin_amdgcn_sinf(tn));
    }
#pragma unroll
    for (int i = 0; i < 8; ++i) {
        int fidx = tid + i * 512;
        float inv = deconv_signed(fidx);
        hbuf[fidx] = make_float2(fr[b * NMODES + fidx] * inv,
                                 fi[b * NMODES + fidx] * inv);
    }
    __syncthreads();

    {
        int n2 = tid;
        float2 acc = make_float2(0.0f, 0.0f);
#pragma unroll
        for (int r = 0; r < 8; ++r) {
            float2 w = w16[((r + 4) * k1) & 15];
            float2 h = hbuf[n2 + 512 * r];
            acc.x = fmaf(h.x, w.x, fmaf(-h.y, w.y, acc.x));
            acc.y = fmaf(h.x, w.y, fmaf( h.y, w.x, acc.y));
        }
        float tn = -(float)(n2 * k1) * 1.220703125e-4f;
        float2 tw = make_float2(__builtin_amdgcn_cosf(tn),
                                __builtin_amdgcn_sinf(tn));
        int rb = (int)(__brev((unsigned)n2) >> 23);
        fbuf[rb] = cmul(acc, tw);
    }
    __syncthreads();

    for (int s = 0; s <= 8; ++s) {
        const int   half = 1 << s;
        const float tscl = -0.5f / (float)half;
        if (tid < 256) {
            int pos = tid & (half - 1);
            int idx = ((tid ^ pos) << 1) | pos;
            float sn = __builtin_amdgcn_sinf(tscl * (float)pos);
            float cs = __builtin_amdgcn_cosf(tscl * (float)pos);
            float2 a = fbuf[idx];
            float2 t = fbuf[idx + half];
            float2 bt = make_float2(t.x * cs - t.y * sn,
                                    t.x * sn + t.y * cs);
            fbuf[idx]        = make_float2(a.x + bt.x, a.y + bt.y);
            fbuf[idx + half] = make_float2(a.x - bt.x, a.y - bt.y);
        }
        __syncthreads();
    }

    const float s2 = ((k1 & 1) ? -1.0f : 1.0f) * GSCALE;
    __half2* base  = g16  + b * GSTRIDE + k1;
    __half*  rbase = gr16 + b * GSTRIDE + k1;
    {
        int j = tid;
        float2 v = fbuf[j];
        float vr = v.x * s2;
        base[16 * j]  = __floats2half2_rn(vr, v.y * s2);
        rbase[16 * j] = __float2half(vr);
    }
    if (tid == 0 && k1 < 8) {   // wrap cell: cell k1 duplicated at 8192+k1
        float2 v = fbuf[0];
        float vr = v.x * s2;
        g16[b * GSTRIDE + NGRID + k1]  = __floats2half2_rn(vr, v.y * s2);
        gr16[b * GSTRIDE + NGRID + k1] = __float2half(vr);
    }
}

// ---------------------------------------------------------------------------
// Interp, cplx=0: 6 scattered USHORT taps from the re-only 16.4 KB slab
// (L1-resident incl. x/out streams). Window math identical to proven R17.
// ---------------------------------------------------------------------------
__global__ __launch_bounds__(1024) void nfft_interp_re_kernel(
    const float* __restrict__ x, const __half* __restrict__ gr16,
    float* __restrict__ out)
{
    const int b   = blockIdx.x & 15;    // co-resident blocks share a batch
    const int blk = blockIdx.x >> 4;
    const int tid = threadIdx.x;

    const __half* gr = gr16 + b * GSTRIDE;
    const int base = b * NPTS + blk * 4096;
    const float4 xv4 = ((const float4*)(x + base))[tid];
    float outre[4];

#pragma unroll
    for (int q = 0; q < 4; ++q) {
        float xv = (q == 0) ? xv4.x : (q == 1) ? xv4.y : (q == 2) ? xv4.z : xv4.w;
        float fl   = xv * 8192.0f;                 // exact (2^13 scale)
        float cf   = ceilf(fl);
        int   c    = (int)cf;
        float frac = cf - fl;                      // [0,1)
        int   wr0  = (c + 12284) & (NGRID - 1);    // (c-4+n/2) mod n
        const __half* gp = gr + wr0;               // taps: gp[1..6]
        float re = 0.0f;
#pragma unroll
        for (int l = 1; l < 7; ++l) {
            float u    = (float)(4 - l) - frac;    // |u| <= 3
            float arg2 = fmaf(-u, u, 16.0f);       // >= 7 > 0
            float r    = rsqrtf(arg2);             // 1/arg
            float z    = arg2 * r * 4.71238898038468986f;  // b*arg
            float w    = __expf(z) * r;
            re = fmaf(w, __half2float(gp[l]), re);
        }
        outre[q] = re * OSCALE;
    }
    ((float4*)(out + base))[tid] =
        make_float4(outre[0], outre[1], outre[2], outre[3]);
}

// ---------------------------------------------------------------------------
// Interp, cplx=1 — byte-identical to green R20.
// ---------------------------------------------------------------------------
__global__ __launch_bounds__(1024) void nfft_interp_kernel(
    const float* __restrict__ x, const __half2* __restrict__ g16,
    float* __restrict__ out, int cplx)
{
    const int b   = blockIdx.x & 15;
    const int blk = blockIdx.x >> 4;
    const int tid = threadIdx.x;

    const __half2* gb = g16 + b * GSTRIDE;
    const int base = b * NPTS + blk * 4096;
    const float4 xv4 = ((const float4*)(x + base))[tid];
    float outre[4], outim[4];

#pragma unroll
    for (int q = 0; q < 4; ++q) {
        float xv = (q == 0) ? xv4.x : (q == 1) ? xv4.y : (q == 2) ? xv4.z : xv4.w;
        float fl   = xv * 8192.0f;
        float cf   = ceilf(fl);
        int   c    = (int)cf;
        float frac = cf - fl;
        int   wr0  = (c + 12284) & (NGRID - 1);
        const __half2* gp = gb + wr0;
        float re = 0.0f, im = 0.0f;
#pragma unroll
        for (int l = 1; l < 7; ++l) {
            float u    = (float)(4 - l) - frac;
            float arg2 = fmaf(-u, u, 16.0f);
            float r    = rsqrtf(arg2);
            float z    = arg2 * r * 4.71238898038468986f;
            float w    = __expf(z) * r;
            float2 gv = __half22float2(gp[l]);
            re = fmaf(w, gv.x, re);
            im = fmaf(w, gv.y, im);
        }
        outre[q] = re * OSCALE;
        outim[q] = im * OSCALE;
    }

    if (cplx) {
        float2* o = ((float2*)out) + base + tid * 4;
        o[0] = make_float2(outre[0], outim[0]);
        o[1] = make_float2(outre[1], outim[1]);
        o[2] = make_float2(outre[2], outim[2]);
        o[3] = make_float2(outre[3], outim[3]);
    } else {
        ((float4*)(out + base))[tid] =
            make_float4(outre[0], outre[1], outre[2], outre[3]);
    }
}

// ---------------------------------------------------------------------------
// Fused single-kernel fallback (proven R4/R7) if d_ws too small.
// ---------------------------------------------------------------------------
__global__ __launch_bounds__(1024) void nfft_fused_kernel(
    const float* __restrict__ x, const float* __restrict__ fr,
    const float* __restrict__ fi, float* __restrict__ out, int cplx)
{
    __shared__ float2 buf[NGRID];
    const int b   = blockIdx.x >> 5;
    const int blk = blockIdx.x & 31;
    const int tid = threadIdx.x;

    for (int j = tid; j < NGRID; j += 1024) {
        float2 v = make_float2(0.0f, 0.0f);
        if (j >= 2048 && j < 6144) {
            int fidx = j - 2048;
            float inv = deconv_signed(fidx);
            v.x = fr[b * NMODES + fidx] * inv;
            v.y = fi[b * NMODES + fidx] * inv;
        }
        buf[j] = v;
    }
    __syncthreads();

    for (int s = 12; s >= 0; --s) {
        const int   half = 1 << s;
        const float tscl = -0.5f / (float)half;
#pragma unroll
        for (int ii = 0; ii < 4; ++ii) {
            int i = tid + ii * 1024;
            int pos = i & (half - 1);
            int idx = ((i ^ pos) << 1) | pos;
            float sn = __builtin_amdgcn_sinf(tscl * (float)pos);
            float cs = __builtin_amdgcn_cosf(tscl * (float)pos);
            float2 a = buf[idx];
            float2 c = buf[idx + half];
            buf[idx] = make_float2(a.x + c.x, a.y + c.y);
            float2 d = make_float2(a.x - c.x, a.y - c.y);
            buf[idx + half] = make_float2(d.x * cs - d.y * sn,
                                          d.x * sn + d.y * cs);
        }
        __syncthreads();
    }

    const int base = b * NPTS + blk * 4096;
    for (int p = tid; p < 4096; p += 1024) {
        float xv   = x[base + p];
        float fl   = xv * 8192.0f;
        int   c    = (int)ceilf(fl);
        float frac = (float)c - fl;
        float re = 0.0f, im = 0.0f;
#pragma unroll
        for (int l = 0; l < 8; ++l) {
            int   ind  = c - 4 + l;
            float u    = (float)(4 - l) - frac;
            float arg2 = 16.0f - u * u;
            float w    = 0.0f;
            if (arg2 > 0.0f) {
                float r   = rsqrtf(arg2);
                float arg = arg2 * r;
                float z   = 4.71238898038468986f * arg;
                w = (__expf(z) - __expf(-z)) * 0.15915494309189533577f * r;
            }
            if (ind & 1) w = -w;
            int wr = (ind + 4096) & (NGRID - 1);
            int rb = (int)(__brev((unsigned)wr) >> 19);
            float2 gv = buf[rb];
            re = fmaf(w, gv.x, re);
            im = fmaf(w, gv.y, im);
        }
        if (cplx) ((float2*)out)[base + p] = make_float2(re, im);
        else      out[base + p] = re;
    }
}

extern "C" void kernel_launch(void* const* d_in, const int* in_sizes, int n_in,
                              void* d_out, int out_size, void* d_ws, size_t ws_size,
                              hipStream_t stream) {
    (void)in_sizes; (void)n_in;
    const float* x  = (const float*)d_in[0];
    const float* fr = (const float*)d_in[1];
    const float* fi = (const float*)d_in[2];

    const int cplx = (out_size >= BATCH * NPTS * 2) ? 1 : 0;
    const size_t g_bytes  = (size_t)BATCH * GSTRIDE * sizeof(__half2);  // 524,800
    const size_t gr_bytes = (size_t)BATCH * GSTRIDE * sizeof(__half);   // 262,400

    if (ws_size >= g_bytes + gr_bytes) {
        __half2* g16  = (__half2*)d_ws;
        __half*  gr16 = (__half*)((char*)d_ws + g_bytes);
        nfft_fft_kernel<<<BATCH * 16, 512, 0, stream>>>(fr, fi, g16, gr16);
        if (!cplx) {
            nfft_interp_re_kernel<<<BATCH * 32, 1024, 0, stream>>>(
                x, gr16, (float*)d_out);
        } else {
            nfft_interp_kernel<<<BATCH * 32, 1024, 0, stream>>>(
                x, g16, (float*)d_out, cplx);
        }
    } else {
        nfft_fused_kernel<<<BATCH * 32, 1024, 0, stream>>>(
            x, fr, fi, (float*)d_out, cplx);
    }
}

// Round 23
// 18.808 us; speedup vs baseline: 1.5253x; 1.1074x over previous
//
#include <hip/hip_runtime.h>
#include <hip/hip_fp16.h>
#include <math.h>

#define NMODES 4096
#define NGRID  8192
#define BATCH  16
#define NPTS   131072
#define GSTRIDE 8200                    // 8192 + 8 wrap cells (u32 each); %4==0
#define GSCALE 1048576.0f               // 2^20 (exact)
#define OSCALE 1.5178830414797062e-07f  // 1/(2*pi*2^20)

__device__ __forceinline__ float2 cmul(float2 a, float2 b) {
    return make_float2(a.x * b.x - a.y * b.y, a.x * b.y + a.y * b.x);
}

// ---------------------------------------------------------------------------
// Deconvolution factor: (-1)^fidx / phi_hat(fidx), I0 asymptotic (z~18).
// ---------------------------------------------------------------------------
__device__ __forceinline__ float deconv_signed(int fidx) {
    float k = (float)(fidx - 2048);
    float t = k * 7.66990393942820614e-4f;                 // 2*pi*k/n
    float z = 4.0f * sqrtf(22.2066099024510563f - t * t);  // m*sqrt(b^2-t^2)
    float iz = 1.0f / z;
    float p  = 1.0f + iz * (0.125f + iz * (0.0703125f +
               iz * (0.0732421875f + iz * 0.112152099609375f)));
    float phi = __expf(z) * p * rsqrtf(6.28318530717958648f * z);
    float s = (fidx & 1) ? -1.0f : 1.0f;
    return s / phi;
}

// ---------------------------------------------------------------------------
// Merged four-step FFT, 512-thread version (proven R20: 18.82us). One block
// per (batch, k1); packed scaled fp16 output + wrap cells.
// ---------------------------------------------------------------------------
__global__ __launch_bounds__(512) void nfft_fft_kernel(
    const float* __restrict__ fr, const float* __restrict__ fi,
    __half2* __restrict__ g16)
{
    __shared__ float2 hbuf[NMODES];  // 32 KB
    __shared__ float2 fbuf[512];     // 4 KB
    __shared__ float2 w16[16];

    const int b   = blockIdx.x >> 4;
    const int k1  = blockIdx.x & 15;
    const int tid = threadIdx.x;     // 0..511

    if (tid < 16) {
        float tn = -(float)tid * 0.0625f;   // -t/16 turns
        w16[tid] = make_float2(__builtin_amdgcn_cosf(tn),
                               __builtin_amdgcn_sinf(tn));
    }
#pragma unroll
    for (int i = 0; i < 8; ++i) {           // coalesced: lanes consecutive
        int fidx = tid + i * 512;
        float inv = deconv_signed(fidx);    // includes (-1)^j sign
        hbuf[fidx] = make_float2(fr[b * NMODES + fidx] * inv,
                                 fi[b * NMODES + fidx] * inv);
    }
    __syncthreads();

    {   // 8-term DFT row: one n2 per thread
        int n2 = tid;
        float2 acc = make_float2(0.0f, 0.0f);
#pragma unroll
        for (int r = 0; r < 8; ++r) {
            float2 w = w16[((r + 4) * k1) & 15];
            float2 h = hbuf[n2 + 512 * r];
            acc.x = fmaf(h.x, w.x, fmaf(-h.y, w.y, acc.x));
            acc.y = fmaf(h.x, w.y, fmaf( h.y, w.x, acc.y));
        }
        float tn = -(float)(n2 * k1) * 1.220703125e-4f;  // -(n2*k1)/8192 turns
        float2 tw = make_float2(__builtin_amdgcn_cosf(tn),
                                __builtin_amdgcn_sinf(tn));
        int rb = (int)(__brev((unsigned)n2) >> 23);      // 9-bit reversal
        fbuf[rb] = cmul(acc, tw);
    }
    __syncthreads();

    for (int s = 0; s <= 8; ++s) {
        const int   half = 1 << s;
        const float tscl = -0.5f / (float)half;          // turns per pos
        if (tid < 256) {                                 // 256 butterflies
            int pos = tid & (half - 1);
            int idx = ((tid ^ pos) << 1) | pos;
            float sn = __builtin_amdgcn_sinf(tscl * (float)pos);
            float cs = __builtin_amdgcn_cosf(tscl * (float)pos);
            float2 a = fbuf[idx];
            float2 t = fbuf[idx + half];
            float2 bt = make_float2(t.x * cs - t.y * sn,
                                    t.x * sn + t.y * cs);
            fbuf[idx]        = make_float2(a.x + bt.x, a.y + bt.y);
            fbuf[idx + half] = make_float2(a.x - bt.x, a.y - bt.y);
        }
        __syncthreads();
    }

    const float s2 = ((k1 & 1) ? -1.0f : 1.0f) * GSCALE;  // sign * 2^20
    __half2* base = g16 + b * GSTRIDE + k1;
    {
        int j = tid;                                      // 512 cells
        float2 v = fbuf[j];
        base[16 * j] = __floats2half2_rn(v.x * s2, v.y * s2);
    }
    if (tid == 0 && k1 < 8) {   // wrap cell: cell k1 duplicated at 8192+k1
        float2 v = fbuf[0];
        g16[b * GSTRIDE + NGRID + k1] = __floats2half2_rn(v.x * s2, v.y * s2);
    }
}

// ---------------------------------------------------------------------------
// Interp — proven R17/R20 kernel (18.82us, absmax 2.0): 6 scattered dword
// taps, full complex accumulation, b=bid&15 L1 remap.
// ---------------------------------------------------------------------------
__global__ __launch_bounds__(1024) void nfft_interp_kernel(
    const float* __restrict__ x, const __half2* __restrict__ g16,
    float* __restrict__ out, int cplx)
{
    const int b   = blockIdx.x & 15;    // co-resident blocks share a batch
    const int blk = blockIdx.x >> 4;
    const int tid = threadIdx.x;

    const __half2* gb = g16 + b * GSTRIDE;
    const int base = b * NPTS + blk * 4096;
    const float4 xv4 = ((const float4*)(x + base))[tid];
    float outre[4], outim[4];

#pragma unroll
    for (int q = 0; q < 4; ++q) {
        float xv = (q == 0) ? xv4.x : (q == 1) ? xv4.y : (q == 2) ? xv4.z : xv4.w;
        float fl   = xv * 8192.0f;                 // exact (2^13 scale)
        float cf   = ceilf(fl);
        int   c    = (int)cf;
        float frac = cf - fl;                      // [0,1)
        int   wr0  = (c + 12284) & (NGRID - 1);    // (c-4+n/2) mod n
        const __half2* gp = gb + wr0;              // taps: gp[1..6]
        float re = 0.0f, im = 0.0f;
#pragma unroll
        for (int l = 1; l < 7; ++l) {
            float u    = (float)(4 - l) - frac;    // n*x - ind, |u| <= 3
            float arg2 = fmaf(-u, u, 16.0f);       // m^2 - u^2 >= 7 > 0
            float r    = rsqrtf(arg2);             // 1/arg
            float z    = arg2 * r * 4.71238898038468986f;  // b*arg
            float w    = __expf(z) * r;            // ~2*sinh(z)/arg (scaled later)
            float2 gv = __half22float2(gp[l]);
            re = fmaf(w, gv.x, re);
            im = fmaf(w, gv.y, im);
        }
        outre[q] = re * OSCALE;
        outim[q] = im * OSCALE;
    }

    if (cplx) {
        float2* o = ((float2*)out) + base + tid * 4;
        o[0] = make_float2(outre[0], outim[0]);
        o[1] = make_float2(outre[1], outim[1]);
        o[2] = make_float2(outre[2], outim[2]);
        o[3] = make_float2(outre[3], outim[3]);
    } else {
        ((float4*)(out + base))[tid] =
            make_float4(outre[0], outre[1], outre[2], outre[3]);
    }
}

// ---------------------------------------------------------------------------
// Fallback: fully fused single kernel (proven R4/R7) if d_ws too small.
// ---------------------------------------------------------------------------
__global__ __launch_bounds__(1024) void nfft_fused_kernel(
    const float* __restrict__ x, const float* __restrict__ fr,
    const float* __restrict__ fi, float* __restrict__ out, int cplx)
{
    __shared__ float2 buf[NGRID];
    const int b   = blockIdx.x >> 5;
    const int blk = blockIdx.x & 31;
    const int tid = threadIdx.x;

    for (int j = tid; j < NGRID; j += 1024) {
        float2 v = make_float2(0.0f, 0.0f);
        if (j >= 2048 && j < 6144) {
            int fidx = j - 2048;
            float inv = deconv_signed(fidx);
            v.x = fr[b * NMODES + fidx] * inv;
            v.y = fi[b * NMODES + fidx] * inv;
        }
        buf[j] = v;
    }
    __syncthreads();

    for (int s = 12; s >= 0; --s) {
        const int   half = 1 << s;
        const float tscl = -0.5f / (float)half;
#pragma unroll
        for (int ii = 0; ii < 4; ++ii) {
            int i = tid + ii * 1024;
            int pos = i & (half - 1);
            int idx = ((i ^ pos) << 1) | pos;
            float sn = __builtin_amdgcn_sinf(tscl * (float)pos);
            float cs = __builtin_amdgcn_cosf(tscl * (float)pos);
            float2 a = buf[idx];
            float2 c = buf[idx + half];
            buf[idx] = make_float2(a.x + c.x, a.y + c.y);
            float2 d = make_float2(a.x - c.x, a.y - c.y);
            buf[idx + half] = make_float2(d.x * cs - d.y * sn,
                                          d.x * sn + d.y * cs);
        }
        __syncthreads();
    }

    const int base = b * NPTS + blk * 4096;
    for (int p = tid; p < 4096; p += 1024) {
        float xv   = x[base + p];
        float fl   = xv * 8192.0f;
        int   c    = (int)ceilf(fl);
        float frac = (float)c - fl;
        float re = 0.0f, im = 0.0f;
#pragma unroll
        for (int l = 0; l < 8; ++l) {
            int   ind  = c - 4 + l;
            float u    = (float)(4 - l) - frac;
            float arg2 = 16.0f - u * u;
            float w    = 0.0f;
            if (arg2 > 0.0f) {
                float r   = rsqrtf(arg2);
                float arg = arg2 * r;
                float z   = 4.71238898038468986f * arg;
                w = (__expf(z) - __expf(-z)) * 0.15915494309189533577f * r;
            }
            if (ind & 1) w = -w;
            int wr = (ind + 4096) & (NGRID - 1);
            int rb = (int)(__brev((unsigned)wr) >> 19);
            float2 gv = buf[rb];
            re = fmaf(w, gv.x, re);
            im = fmaf(w, gv.y, im);
        }
        if (cplx) ((float2*)out)[base + p] = make_float2(re, im);
        else      out[base + p] = re;
    }
}

extern "C" void kernel_launch(void* const* d_in, const int* in_sizes, int n_in,
                              void* d_out, int out_size, void* d_ws, size_t ws_size,
                              hipStream_t stream) {
    (void)in_sizes; (void)n_in;
    const float* x  = (const float*)d_in[0];
    const float* fr = (const float*)d_in[1];
    const float* fi = (const float*)d_in[2];

    const int cplx = (out_size >= BATCH * NPTS * 2) ? 1 : 0;
    const size_t g_bytes = (size_t)BATCH * GSTRIDE * sizeof(__half2);  // 525 KB

    if (ws_size >= g_bytes) {
        __half2* g16 = (__half2*)d_ws;
        nfft_fft_kernel<<<BATCH * 16, 512, 0, stream>>>(fr, fi, g16);
        nfft_interp_kernel<<<BATCH * 32, 1024, 0, stream>>>(
            x, g16, (float*)d_out, cplx);
    } else {
        nfft_fused_kernel<<<BATCH * 32, 1024, 0, stream>>>(
            x, fr, fi, (float*)d_out, cplx);
    }
}